// Round 7
// baseline (7099.733 us; speedup 1.0000x reference)
//
#include <hip/hip_runtime.h>

// SentimentLSTM: B=64, T=512, E=128, H=256, V=100000, O=1
// outputs: sig_out[64], hT[1,64,256], cT[1,64,256] -> 32832 f32
//
// k_rec: 8 blocks = 4 groups x 2 halves, 512 thr.
//   block (grp, half): batches grp*16..+15, units half*128..+127, all 4 gates.
//   MFMA operands SWAPPED: mfma(W, h) -> lane = batch (col), regs = 4
//   consecutive units (rows). Exchange u64s {2 bf16, tag} are unit-major and
//   feed the partner's MFMA B-fragments DIRECTLY from registers (no LDS, no
//   2nd barrier). Split-K: own-half MFMAs + gx C-init execute between the
//   exchange store and the poll, hiding the coherence round trip.
//   Head h.weff fused as 8 MFMAs reusing the same fragments.
//
// ws layout:
//   gx   bf16 [T][B][4H] natural, bias=b_ih+b_hh folded   67,108,864 B
//   hx   u64  [2 par][8 slot][16 b][64 pair]                 131,072 B
//   weff f32  [257]                                            1,028 B

#define BATCH 64
#define TSTEPS 512
#define EDIM 128
#define HDIM 256
#define G4H 1024

typedef short bf16x8 __attribute__((ext_vector_type(8)));
typedef short bf16x4 __attribute__((ext_vector_type(4)));
typedef float f32x4 __attribute__((ext_vector_type(4)));

__device__ __forceinline__ unsigned short f2bf(float f) {
  unsigned u = __builtin_bit_cast(unsigned, f);
  return (unsigned short)((u + 0x7fffu + ((u >> 16) & 1u)) >> 16);
}
__device__ __forceinline__ float bf2f(unsigned short h) {
  unsigned u = ((unsigned)h) << 16;
  return __builtin_bit_cast(float, u);
}
__device__ __forceinline__ unsigned pk2(float a, float b) {
  return (unsigned)f2bf(a) | ((unsigned)f2bf(b) << 16);
}
__device__ __forceinline__ float fsig(float x) {
  return __builtin_amdgcn_rcpf(1.f + __expf(-x));
}
__device__ __forceinline__ float ftanh(float x) {
  return 1.f - 2.f * __builtin_amdgcn_rcpf(__expf(2.f * x) + 1.f);
}
__device__ __forceinline__ bf16x8 ldfrag(const unsigned short* p) {
  bf16x4 a = *(const bf16x4*)p;
  bf16x4 b = *(const bf16x4*)(p + 16);
  return __builtin_shufflevector(a, b, 0, 1, 2, 3, 4, 5, 6, 7);
}
__device__ __forceinline__ bf16x8 pack8(float4 v0, float4 v1) {
  bf16x8 f;
  f[0] = (short)f2bf(v0.x); f[1] = (short)f2bf(v0.y);
  f[2] = (short)f2bf(v0.z); f[3] = (short)f2bf(v0.w);
  f[4] = (short)f2bf(v1.x); f[5] = (short)f2bf(v1.y);
  f[6] = (short)f2bf(v1.z); f[7] = (short)f2bf(v1.w);
  return f;
}

// ---------------- K1: gx[t][b][col] = emb[x] @ W_ih^T + (b_ih + b_hh) -------
__global__ __launch_bounds__(256) void k_gx(const int* __restrict__ x,
                                            const float* __restrict__ emb,
                                            const float* __restrict__ Wih,
                                            const float* __restrict__ bih,
                                            const float* __restrict__ bhh,
                                            unsigned short* __restrict__ gx) {
  const int t = blockIdx.x;
  const int g0 = blockIdx.y * 64;
  const int tid = threadIdx.x;
  __shared__ unsigned short Al[64 * 136];
  __shared__ unsigned short Bl[64 * 136];
  __shared__ int tok[64];
  if (tid < 64) tok[tid] = x[tid * TSTEPS + t];
  __syncthreads();
  {
    const int r = tid >> 2, c0 = (tid & 3) * 32;
    const float* asrc = emb + (size_t)tok[r] * EDIM + c0;
    const float* bsrc = Wih + (size_t)(g0 + r) * EDIM + c0;
#pragma unroll
    for (int s = 0; s < 32; s += 8) {
      float4 a0 = *(const float4*)(asrc + s);
      float4 a1 = *(const float4*)(asrc + s + 4);
      uint4 pa = {pk2(a0.x, a0.y), pk2(a0.z, a0.w), pk2(a1.x, a1.y), pk2(a1.z, a1.w)};
      *(uint4*)&Al[r * 136 + c0 + s] = pa;
      float4 b0 = *(const float4*)(bsrc + s);
      float4 b1 = *(const float4*)(bsrc + s + 4);
      uint4 pb = {pk2(b0.x, b0.y), pk2(b0.z, b0.w), pk2(b1.x, b1.y), pk2(b1.z, b1.w)};
      *(uint4*)&Bl[r * 136 + c0 + s] = pb;
    }
  }
  __syncthreads();
  const int lane = tid & 63, w = tid >> 6;
  const int lo = lane & 15, hi = lane >> 4;
  const int mb = (w & 1) * 32, nb = (w >> 1) * 32;
  f32x4 acc[2][2];
#pragma unroll
  for (int jj = 0; jj < 2; ++jj) {
    const int col = g0 + nb + jj * 16 + lo;
    float bv = bih[col] + bhh[col];
    acc[0][jj] = (f32x4){bv, bv, bv, bv};
    acc[1][jj] = acc[0][jj];
  }
#pragma unroll
  for (int kk = 0; kk < 4; ++kk) {
    bf16x8 af0 = ldfrag(&Al[(mb + lo) * 136 + kk * 32 + hi * 4]);
    bf16x8 af1 = ldfrag(&Al[(mb + 16 + lo) * 136 + kk * 32 + hi * 4]);
    bf16x8 bf0 = ldfrag(&Bl[(nb + lo) * 136 + kk * 32 + hi * 4]);
    bf16x8 bf1 = ldfrag(&Bl[(nb + 16 + lo) * 136 + kk * 32 + hi * 4]);
    acc[0][0] = __builtin_amdgcn_mfma_f32_16x16x32_bf16(af0, bf0, acc[0][0], 0, 0, 0);
    acc[0][1] = __builtin_amdgcn_mfma_f32_16x16x32_bf16(af0, bf1, acc[0][1], 0, 0, 0);
    acc[1][0] = __builtin_amdgcn_mfma_f32_16x16x32_bf16(af1, bf0, acc[1][0], 0, 0, 0);
    acc[1][1] = __builtin_amdgcn_mfma_f32_16x16x32_bf16(af1, bf1, acc[1][1], 0, 0, 0);
  }
#pragma unroll
  for (int i = 0; i < 2; ++i)
#pragma unroll
    for (int jj = 0; jj < 2; ++jj)
#pragma unroll
      for (int r = 0; r < 4; ++r) {
        int m = mb + i * 16 + hi * 4 + r;
        int col = g0 + nb + jj * 16 + lo;
        gx[(size_t)(t * BATCH + m) * G4H + col] = f2bf(acc[i][jj][r]);
      }
}

// ---------------- K2: recurrence, split-K latency hiding --------------------
__global__ __launch_bounds__(512, 2) void k_rec(const unsigned short* __restrict__ gx,
                                                const float* __restrict__ Whh,
                                                const float* __restrict__ weff,
                                                unsigned long long* __restrict__ hx,
                                                float* __restrict__ out) {
  const int tid = threadIdx.x;
  const int bp = blockIdx.x;              // 0..7
  const int grp = bp >> 1, half = bp & 1;
  const int b0 = grp * 16;
  const int lane = tid & 63, w = tid >> 6;
  const int lo = lane & 15, hi = lane >> 4;
  const int kOwn = half * 4, kPar = (half ^ 1) * 4;  // kk_abs ranges
  const int myslot = bp, pslot = bp ^ 1;
  __shared__ unsigned short h_lds[2][16 * 136];      // [buf][batch][128 own units + pad]
  // W fragments (A-operand: lane lo = output-unit row within wave tile)
  bf16x8 wf[4][8];
#pragma unroll
  for (int g = 0; g < 4; ++g) {
    const float* wr = Whh + (size_t)(g * 256 + half * 128 + w * 16 + lo) * HDIM;
#pragma unroll
    for (int kk = 0; kk < 8; ++kk) {
      const float* p = wr + kk * 32 + hi * 8;
      wf[g][kk] = pack8(*(const float4*)p, *(const float4*)(p + 4));
    }
  }
  // weff fragments (A-operand, replicated over m)
  bf16x8 wef[8];
#pragma unroll
  for (int kk = 0; kk < 8; ++kk) {
    const float* p = weff + kk * 32 + hi * 8;
    wef[kk] = pack8(*(const float4*)p, *(const float4*)(p + 4));
  }
  const float c0 = weff[256];
  // gx base for this lane (batch = b0+lo), natural layout; per-t stride 65536 u16
  const unsigned short* gbase = gx + (size_t)(b0 + lo) * G4H + half * 128 + w * 16 + hi * 4;
  f32x4 acc[4], hacc = (f32x4){0.f, 0.f, 0.f, 0.f};
  float c[4] = {0.f, 0.f, 0.f, 0.f};
  float hvP[4];
  float sig_acc = 0.f;
  ushort4 gEven[4], gOdd[4];
  // prologue: gx(0) -> acc (h(0)=0 so no MFMA); issue gx(1)
  {
    ushort4 g0v[4];
#pragma unroll
    for (int g = 0; g < 4; ++g) g0v[g] = *(const ushort4*)(gbase + g * 256);
#pragma unroll
    for (int g = 0; g < 4; ++g) {
      acc[g][0] = bf2f(g0v[g].x); acc[g][1] = bf2f(g0v[g].y);
      acc[g][2] = bf2f(g0v[g].z); acc[g][3] = bf2f(g0v[g].w);
    }
#pragma unroll
    for (int g = 0; g < 4; ++g) gOdd[g] = *(const ushort4*)(gbase + 65536 + g * 256);
  }
  auto step = [&](int t, ushort4 (&gcons)[4], ushort4 (&gissue)[4]) {
    const unsigned wt = (unsigned)(t + 1);
    // ---- poll partner h(t) as register fragments; partner gate+head MFMAs
    if (t > 0) {
      const int par = t & 1;
      const unsigned long long* src =
          hx + ((size_t)(par * 8 + pslot) * 16 + lo) * 64 + hi * 4;
      unsigned long long v[16];
      unsigned mism;
      const unsigned tagv = (unsigned)t;
      do {
        mism = 0u;
#pragma unroll
        for (int kk = 0; kk < 4; ++kk)
#pragma unroll
          for (int q = 0; q < 4; ++q)
            v[kk * 4 + q] = __hip_atomic_load(src + kk * 16 + q, __ATOMIC_RELAXED,
                                              __HIP_MEMORY_SCOPE_AGENT);
#pragma unroll
        for (int i = 0; i < 16; ++i)
          mism |= ((unsigned)(v[i] >> 32)) ^ tagv;
      } while (__any(mism != 0u));
#pragma unroll
      for (int kk = 0; kk < 4; ++kk) {
        uint4 dv = {(unsigned)v[kk * 4 + 0], (unsigned)v[kk * 4 + 1],
                    (unsigned)v[kk * 4 + 2], (unsigned)v[kk * 4 + 3]};
        bf16x8 pa = __builtin_bit_cast(bf16x8, dv);
        acc[0] = __builtin_amdgcn_mfma_f32_16x16x32_bf16(wf[0][kPar + kk], pa, acc[0], 0, 0, 0);
        acc[1] = __builtin_amdgcn_mfma_f32_16x16x32_bf16(wf[1][kPar + kk], pa, acc[1], 0, 0, 0);
        acc[2] = __builtin_amdgcn_mfma_f32_16x16x32_bf16(wf[2][kPar + kk], pa, acc[2], 0, 0, 0);
        acc[3] = __builtin_amdgcn_mfma_f32_16x16x32_bf16(wf[3][kPar + kk], pa, acc[3], 0, 0, 0);
        hacc = __builtin_amdgcn_mfma_f32_16x16x32_bf16(wef[kPar + kk], pa, hacc, 0, 0, 0);
      }
      sig_acc += fsig(hacc[0] + c0);  // head for h(t): all lanes hold batch lo's dot
    }
    // ---- issue gx(t+2) EARLY so in-order vmcnt never gates the next poll
    if (t + 2 <= TSTEPS - 1) {
      const unsigned short* q = gbase + (size_t)(t + 2) * 65536;
#pragma unroll
      for (int g = 0; g < 4; ++g) gissue[g] = *(const ushort4*)(q + g * 256);
    }
    // ---- cell update: lane holds (batch=lo, units u0..u0+3) with i,f,g,o
    unsigned short hb[4];
#pragma unroll
    for (int r = 0; r < 4; ++r) {
      float iv = fsig(acc[0][r]), fv = fsig(acc[1][r]);
      float gv = ftanh(acc[2][r]), ov = fsig(acc[3][r]);
      c[r] = fv * c[r] + iv * gv;
      hvP[r] = ov * ftanh(c[r]);
      hb[r] = f2bf(hvP[r]);
    }
    // ---- tagged exchange store (unit-major: directly partner-consumable)
    {
      const int spar = (int)(wt & 1u);
      unsigned long long* dst =
          hx + ((size_t)(spar * 8 + myslot) * 16 + lo) * 64 + (w * 8 + hi * 2);
      const unsigned long long tg = ((unsigned long long)wt) << 32;
      __hip_atomic_store(dst + 0,
                         tg | (unsigned long long)pk2(hvP[0], hvP[1]),
                         __ATOMIC_RELAXED, __HIP_MEMORY_SCOPE_AGENT);
      __hip_atomic_store(dst + 1,
                         tg | (unsigned long long)pk2(hvP[2], hvP[3]),
                         __ATOMIC_RELAXED, __HIP_MEMORY_SCOPE_AGENT);
      // forbid the compiler from sinking these stores past any later spin loop
      asm volatile("" ::: "memory");
    }
    // ---- own half -> LDS, barrier, own fragments, head-own + next C-init/MFMA
    const int buf = (int)(wt & 1u);
    *(ushort4*)&h_lds[buf][lo * 136 + w * 16 + hi * 4] =
        (ushort4){(unsigned short)hb[0], (unsigned short)hb[1],
                  (unsigned short)hb[2], (unsigned short)hb[3]};
    __syncthreads();
    if (t < TSTEPS - 1) {
#pragma unroll
      for (int g = 0; g < 4; ++g) {
        acc[g][0] = bf2f(gcons[g].x); acc[g][1] = bf2f(gcons[g].y);
        acc[g][2] = bf2f(gcons[g].z); acc[g][3] = bf2f(gcons[g].w);
      }
    }
    hacc = (f32x4){0.f, 0.f, 0.f, 0.f};
#pragma unroll
    for (int kk = 0; kk < 4; ++kk) {
      bf16x8 oa = *(const bf16x8*)&h_lds[buf][lo * 136 + kk * 32 + hi * 8];
      hacc = __builtin_amdgcn_mfma_f32_16x16x32_bf16(wef[kOwn + kk], oa, hacc, 0, 0, 0);
      if (t < TSTEPS - 1) {
        acc[0] = __builtin_amdgcn_mfma_f32_16x16x32_bf16(wf[0][kOwn + kk], oa, acc[0], 0, 0, 0);
        acc[1] = __builtin_amdgcn_mfma_f32_16x16x32_bf16(wf[1][kOwn + kk], oa, acc[1], 0, 0, 0);
        acc[2] = __builtin_amdgcn_mfma_f32_16x16x32_bf16(wf[2][kOwn + kk], oa, acc[2], 0, 0, 0);
        acc[3] = __builtin_amdgcn_mfma_f32_16x16x32_bf16(wf[3][kOwn + kk], oa, acc[3], 0, 0, 0);
      }
    }
  };
  for (int t = 0; t < TSTEPS; t += 2) {
    step(t, gOdd, gEven);       // consume gx(t+1) [odd], issue gx(t+2) [even]
    step(t + 1, gEven, gOdd);   // consume gx(t+2) [even], issue gx(t+3) [odd]
  }
  // ---- epilogue: head for h(512) (poll tag 512, parity 0), outputs
  {
    const unsigned long long* src =
        hx + ((size_t)(0 * 8 + pslot) * 16 + lo) * 64 + hi * 4;
    unsigned long long v[16];
    unsigned mism;
    const unsigned tagv = (unsigned)TSTEPS;
    do {
      mism = 0u;
#pragma unroll
      for (int kk = 0; kk < 4; ++kk)
#pragma unroll
        for (int q = 0; q < 4; ++q)
          v[kk * 4 + q] = __hip_atomic_load(src + kk * 16 + q, __ATOMIC_RELAXED,
                                            __HIP_MEMORY_SCOPE_AGENT);
#pragma unroll
      for (int i = 0; i < 16; ++i)
        mism |= ((unsigned)(v[i] >> 32)) ^ tagv;
    } while (__any(mism != 0u));
#pragma unroll
    for (int kk = 0; kk < 4; ++kk) {
      uint4 dv = {(unsigned)v[kk * 4 + 0], (unsigned)v[kk * 4 + 1],
                  (unsigned)v[kk * 4 + 2], (unsigned)v[kk * 4 + 3]};
      bf16x8 pa = __builtin_bit_cast(bf16x8, dv);
      hacc = __builtin_amdgcn_mfma_f32_16x16x32_bf16(wef[kPar + kk], pa, hacc, 0, 0, 0);
    }
    sig_acc += fsig(hacc[0] + c0);
  }
  if (w == 0 && hi == 0 && half == 0) out[b0 + lo] = sig_acc * (1.f / 512.f);
  {
    const int u0 = half * 128 + w * 16 + hi * 4;
    float4 ho = {hvP[0], hvP[1], hvP[2], hvP[3]};
    float4 co = {c[0], c[1], c[2], c[3]};
    *(float4*)&out[64 + (size_t)(b0 + lo) * HDIM + u0] = ho;
    *(float4*)&out[64 + BATCH * HDIM + (size_t)(b0 + lo) * HDIM + u0] = co;
  }
}

// ---------------- K3: w_eff[k] = sum_j Wf[j]*Wm[j][k]; weff[256] = bm.Wf+bf --
__global__ __launch_bounds__(256) void k_weff(const float* __restrict__ Wm,
                                              const float* __restrict__ bm,
                                              const float* __restrict__ Wf,
                                              const float* __restrict__ bfb,
                                              float* __restrict__ weff) {
  const int k = threadIdx.x;
  __shared__ float red[256];
  float acc = 0.f;
#pragma unroll 8
  for (int jj = 0; jj < 256; ++jj) acc += Wf[jj] * Wm[jj * 256 + k];
  weff[k] = acc;
  red[k] = bm[k] * Wf[k];
  __syncthreads();
  for (int s = 128; s > 0; s >>= 1) {
    if (k < s) red[k] += red[k + s];
    __syncthreads();
  }
  if (k == 0) weff[256] = red[0] + bfb[0];
}

extern "C" void kernel_launch(void* const* d_in, const int* in_sizes, int n_in,
                              void* d_out, int out_size, void* d_ws, size_t ws_size,
                              hipStream_t stream) {
  (void)in_sizes; (void)n_in; (void)out_size; (void)ws_size;
  const int* x = (const int*)d_in[0];
  const float* emb = (const float*)d_in[1];
  const float* Wih = (const float*)d_in[2];
  const float* Whh = (const float*)d_in[3];
  const float* bih = (const float*)d_in[4];
  const float* bhh = (const float*)d_in[5];
  const float* Wm  = (const float*)d_in[6];
  const float* bm  = (const float*)d_in[7];
  const float* Wf  = (const float*)d_in[8];
  const float* bf  = (const float*)d_in[9];
  float* out = (float*)d_out;
  char* ws = (char*)d_ws;
  const size_t gx_bytes = (size_t)TSTEPS * BATCH * G4H * 2;  // 67,108,864
  const size_t hx_bytes = (size_t)2 * 8 * 16 * 64 * 8;       // 131,072
  unsigned short* gx = (unsigned short*)ws;
  unsigned long long* hx = (unsigned long long*)(ws + gx_bytes);
  float* weff = (float*)(ws + gx_bytes + hx_bytes);
  hipMemsetAsync(hx, 0, hx_bytes, stream);  // tags start at 0 every launch
  k_gx<<<dim3(512, 16), 256, 0, stream>>>(x, emb, Wih, bih, bhh, gx);
  k_weff<<<1, 256, 0, stream>>>(Wm, bm, Wf, bf, weff);
  k_rec<<<8, 512, 0, stream>>>(gx, Whh, weff, hx, out);
}

// Round 8
// 2911.020 us; speedup vs baseline: 2.4389x; 2.4389x over previous
//
#include <hip/hip_runtime.h>

// SentimentLSTM: B=64, T=512, E=128, H=256, V=100000, O=1
// outputs: sig_out[64], hT[1,64,256], cT[1,64,256] -> 32832 f32
//
// k_rec: 8 blocks = 4 groups x 2 halves, 512 thr.
//   block (grp, half): batches grp*16..+15, units half*128..+127, all 4 gates.
//   mfma(W, h): lane = batch (col), regs = 4 consecutive units (rows).
//   Exchange u64s {2 bf16, tag} are unit-major -> partner MFMA B-fragments
//   directly from registers. Split-K: own-half MFMAs + gx C-init run between
//   exchange store and poll, hiding the coherence RT. Head fused as MFMAs.
//   W fragments: STATIC-INDEXED arrays wfO/wfP (rule #20: runtime-indexed
//   ext_vector arrays are demoted to scratch — this was R7's 7x regression).
//
// ws layout:
//   gx   bf16 [T][B][4H] natural, bias=b_ih+b_hh folded   67,108,864 B
//   hx   u64  [2 par][8 slot][16 b][64 pair]                 131,072 B
//   weff f32  [257]                                            1,028 B

#define BATCH 64
#define TSTEPS 512
#define EDIM 128
#define HDIM 256
#define G4H 1024

typedef short bf16x8 __attribute__((ext_vector_type(8)));
typedef short bf16x4 __attribute__((ext_vector_type(4)));
typedef float f32x4 __attribute__((ext_vector_type(4)));

__device__ __forceinline__ unsigned short f2bf(float f) {
  unsigned u = __builtin_bit_cast(unsigned, f);
  return (unsigned short)((u + 0x7fffu + ((u >> 16) & 1u)) >> 16);
}
__device__ __forceinline__ float bf2f(unsigned short h) {
  unsigned u = ((unsigned)h) << 16;
  return __builtin_bit_cast(float, u);
}
__device__ __forceinline__ unsigned pk2(float a, float b) {
  return (unsigned)f2bf(a) | ((unsigned)f2bf(b) << 16);
}
__device__ __forceinline__ float fsig(float x) {
  return __builtin_amdgcn_rcpf(1.f + __expf(-x));
}
__device__ __forceinline__ float ftanh(float x) {
  return 1.f - 2.f * __builtin_amdgcn_rcpf(__expf(2.f * x) + 1.f);
}
__device__ __forceinline__ bf16x8 ldfrag(const unsigned short* p) {
  bf16x4 a = *(const bf16x4*)p;
  bf16x4 b = *(const bf16x4*)(p + 16);
  return __builtin_shufflevector(a, b, 0, 1, 2, 3, 4, 5, 6, 7);
}
__device__ __forceinline__ bf16x8 pack8(float4 v0, float4 v1) {
  bf16x8 f;
  f[0] = (short)f2bf(v0.x); f[1] = (short)f2bf(v0.y);
  f[2] = (short)f2bf(v0.z); f[3] = (short)f2bf(v0.w);
  f[4] = (short)f2bf(v1.x); f[5] = (short)f2bf(v1.y);
  f[6] = (short)f2bf(v1.z); f[7] = (short)f2bf(v1.w);
  return f;
}

// ---------------- K1: gx[t][b][col] = emb[x] @ W_ih^T + (b_ih + b_hh) -------
__global__ __launch_bounds__(256) void k_gx(const int* __restrict__ x,
                                            const float* __restrict__ emb,
                                            const float* __restrict__ Wih,
                                            const float* __restrict__ bih,
                                            const float* __restrict__ bhh,
                                            unsigned short* __restrict__ gx) {
  const int t = blockIdx.x;
  const int g0 = blockIdx.y * 64;
  const int tid = threadIdx.x;
  __shared__ unsigned short Al[64 * 136];
  __shared__ unsigned short Bl[64 * 136];
  __shared__ int tok[64];
  if (tid < 64) tok[tid] = x[tid * TSTEPS + t];
  __syncthreads();
  {
    const int r = tid >> 2, c0 = (tid & 3) * 32;
    const float* asrc = emb + (size_t)tok[r] * EDIM + c0;
    const float* bsrc = Wih + (size_t)(g0 + r) * EDIM + c0;
#pragma unroll
    for (int s = 0; s < 32; s += 8) {
      float4 a0 = *(const float4*)(asrc + s);
      float4 a1 = *(const float4*)(asrc + s + 4);
      uint4 pa = {pk2(a0.x, a0.y), pk2(a0.z, a0.w), pk2(a1.x, a1.y), pk2(a1.z, a1.w)};
      *(uint4*)&Al[r * 136 + c0 + s] = pa;
      float4 b0 = *(const float4*)(bsrc + s);
      float4 b1 = *(const float4*)(bsrc + s + 4);
      uint4 pb = {pk2(b0.x, b0.y), pk2(b0.z, b0.w), pk2(b1.x, b1.y), pk2(b1.z, b1.w)};
      *(uint4*)&Bl[r * 136 + c0 + s] = pb;
    }
  }
  __syncthreads();
  const int lane = tid & 63, w = tid >> 6;
  const int lo = lane & 15, hi = lane >> 4;
  const int mb = (w & 1) * 32, nb = (w >> 1) * 32;
  f32x4 acc[2][2];
#pragma unroll
  for (int jj = 0; jj < 2; ++jj) {
    const int col = g0 + nb + jj * 16 + lo;
    float bv = bih[col] + bhh[col];
    acc[0][jj] = (f32x4){bv, bv, bv, bv};
    acc[1][jj] = acc[0][jj];
  }
#pragma unroll
  for (int kk = 0; kk < 4; ++kk) {
    bf16x8 af0 = ldfrag(&Al[(mb + lo) * 136 + kk * 32 + hi * 4]);
    bf16x8 af1 = ldfrag(&Al[(mb + 16 + lo) * 136 + kk * 32 + hi * 4]);
    bf16x8 bf0 = ldfrag(&Bl[(nb + lo) * 136 + kk * 32 + hi * 4]);
    bf16x8 bf1 = ldfrag(&Bl[(nb + 16 + lo) * 136 + kk * 32 + hi * 4]);
    acc[0][0] = __builtin_amdgcn_mfma_f32_16x16x32_bf16(af0, bf0, acc[0][0], 0, 0, 0);
    acc[0][1] = __builtin_amdgcn_mfma_f32_16x16x32_bf16(af0, bf1, acc[0][1], 0, 0, 0);
    acc[1][0] = __builtin_amdgcn_mfma_f32_16x16x32_bf16(af1, bf0, acc[1][0], 0, 0, 0);
    acc[1][1] = __builtin_amdgcn_mfma_f32_16x16x32_bf16(af1, bf1, acc[1][1], 0, 0, 0);
  }
#pragma unroll
  for (int i = 0; i < 2; ++i)
#pragma unroll
    for (int jj = 0; jj < 2; ++jj)
#pragma unroll
      for (int r = 0; r < 4; ++r) {
        int m = mb + i * 16 + hi * 4 + r;
        int col = g0 + nb + jj * 16 + lo;
        gx[(size_t)(t * BATCH + m) * G4H + col] = f2bf(acc[i][jj][r]);
      }
}

// ---------------- K2: recurrence, split-K latency hiding --------------------
__global__ __launch_bounds__(512, 2) void k_rec(const unsigned short* __restrict__ gx,
                                                const float* __restrict__ Whh,
                                                const float* __restrict__ weff,
                                                unsigned long long* __restrict__ hx,
                                                float* __restrict__ out) {
  const int tid = threadIdx.x;
  const int bp = blockIdx.x;              // 0..7
  const int grp = bp >> 1, half = bp & 1;
  const int b0 = grp * 16;
  const int lane = tid & 63, w = tid >> 6;
  const int lo = lane & 15, hi = lane >> 4;
  const int kOwnBase = half * 4, kParBase = (half ^ 1) * 4;  // k-subtile bases
  const int myslot = bp, pslot = bp ^ 1;
  __shared__ unsigned short h_lds[2][16 * 136];  // [buf][batch][128 own units + pad]
  // W fragments, STATIC register indices; runtime only in the LOAD ADDRESS.
  // wfO[g][kk] = W[g*256+unit][(kOwnBase+kk)*32 + hi*8 ..], own-half K cols
  // wfP[g][kk] = same row, partner-half K cols
  bf16x8 wfO[4][4], wfP[4][4];
#pragma unroll
  for (int g = 0; g < 4; ++g) {
    const float* wr = Whh + (size_t)(g * 256 + half * 128 + w * 16 + lo) * HDIM;
#pragma unroll
    for (int kk = 0; kk < 4; ++kk) {
      const float* pO = wr + (kOwnBase + kk) * 32 + hi * 8;
      const float* pP = wr + (kParBase + kk) * 32 + hi * 8;
      wfO[g][kk] = pack8(*(const float4*)pO, *(const float4*)(pO + 4));
      wfP[g][kk] = pack8(*(const float4*)pP, *(const float4*)(pP + 4));
    }
  }
  bf16x8 wefO[4], wefP[4];
#pragma unroll
  for (int kk = 0; kk < 4; ++kk) {
    const float* pO = weff + (kOwnBase + kk) * 32 + hi * 8;
    const float* pP = weff + (kParBase + kk) * 32 + hi * 8;
    wefO[kk] = pack8(*(const float4*)pO, *(const float4*)(pO + 4));
    wefP[kk] = pack8(*(const float4*)pP, *(const float4*)(pP + 4));
  }
  const float c0 = weff[256];
  // gx base for this lane (batch = b0+lo), natural layout; per-t stride 65536 u16
  const unsigned short* gbase = gx + (size_t)(b0 + lo) * G4H + half * 128 + w * 16 + hi * 4;
  f32x4 acc[4], hacc = (f32x4){0.f, 0.f, 0.f, 0.f};
  float c[4] = {0.f, 0.f, 0.f, 0.f};
  float hvP[4];
  float sig_acc = 0.f;
  ushort4 gEven[4], gOdd[4];
  // prologue: gx(0) -> acc (h(0)=0 so no MFMA); issue gx(1)
  {
    ushort4 g0v[4];
#pragma unroll
    for (int g = 0; g < 4; ++g) g0v[g] = *(const ushort4*)(gbase + g * 256);
#pragma unroll
    for (int g = 0; g < 4; ++g) {
      acc[g][0] = bf2f(g0v[g].x); acc[g][1] = bf2f(g0v[g].y);
      acc[g][2] = bf2f(g0v[g].z); acc[g][3] = bf2f(g0v[g].w);
    }
#pragma unroll
    for (int g = 0; g < 4; ++g) gOdd[g] = *(const ushort4*)(gbase + 65536 + g * 256);
  }
  auto step = [&](int t, ushort4 (&gcons)[4], ushort4 (&gissue)[4]) {
    const unsigned wt = (unsigned)(t + 1);
    // ---- poll partner h(t) as register fragments; partner gate+head MFMAs
    if (t > 0) {
      const int par = t & 1;
      const unsigned long long* src =
          hx + ((size_t)(par * 8 + pslot) * 16 + lo) * 64 + hi * 4;
      unsigned long long v[16];
      unsigned mism;
      const unsigned tagv = (unsigned)t;
      do {
        mism = 0u;
#pragma unroll
        for (int kk = 0; kk < 4; ++kk)
#pragma unroll
          for (int q = 0; q < 4; ++q)
            v[kk * 4 + q] = __hip_atomic_load(src + kk * 16 + q, __ATOMIC_RELAXED,
                                              __HIP_MEMORY_SCOPE_AGENT);
#pragma unroll
        for (int i = 0; i < 16; ++i)
          mism |= ((unsigned)(v[i] >> 32)) ^ tagv;
      } while (__any(mism != 0u));
#pragma unroll
      for (int kk = 0; kk < 4; ++kk) {
        uint4 dv = {(unsigned)v[kk * 4 + 0], (unsigned)v[kk * 4 + 1],
                    (unsigned)v[kk * 4 + 2], (unsigned)v[kk * 4 + 3]};
        bf16x8 pa = __builtin_bit_cast(bf16x8, dv);
        acc[0] = __builtin_amdgcn_mfma_f32_16x16x32_bf16(wfP[0][kk], pa, acc[0], 0, 0, 0);
        acc[1] = __builtin_amdgcn_mfma_f32_16x16x32_bf16(wfP[1][kk], pa, acc[1], 0, 0, 0);
        acc[2] = __builtin_amdgcn_mfma_f32_16x16x32_bf16(wfP[2][kk], pa, acc[2], 0, 0, 0);
        acc[3] = __builtin_amdgcn_mfma_f32_16x16x32_bf16(wfP[3][kk], pa, acc[3], 0, 0, 0);
        hacc = __builtin_amdgcn_mfma_f32_16x16x32_bf16(wefP[kk], pa, hacc, 0, 0, 0);
      }
      sig_acc += fsig(hacc[0] + c0);  // head for h(t): lane holds batch lo's dot
    }
    // ---- issue gx(t+2) EARLY so in-order vmcnt never gates the next poll
    if (t + 2 <= TSTEPS - 1) {
      const unsigned short* q = gbase + (size_t)(t + 2) * 65536;
#pragma unroll
      for (int g = 0; g < 4; ++g) gissue[g] = *(const ushort4*)(q + g * 256);
    }
    // ---- cell update: lane holds (batch=lo, units u0..u0+3) with i,f,g,o
    unsigned short hb[4];
#pragma unroll
    for (int r = 0; r < 4; ++r) {
      float iv = fsig(acc[0][r]), fv = fsig(acc[1][r]);
      float gv = ftanh(acc[2][r]), ov = fsig(acc[3][r]);
      c[r] = fv * c[r] + iv * gv;
      hvP[r] = ov * ftanh(c[r]);
      hb[r] = f2bf(hvP[r]);
    }
    // ---- tagged exchange store (unit-major: directly partner-consumable)
    {
      const int spar = (int)(wt & 1u);
      unsigned long long* dst =
          hx + ((size_t)(spar * 8 + myslot) * 16 + lo) * 64 + (w * 8 + hi * 2);
      const unsigned long long tg = ((unsigned long long)wt) << 32;
      __hip_atomic_store(dst + 0,
                         tg | (unsigned long long)pk2(hvP[0], hvP[1]),
                         __ATOMIC_RELAXED, __HIP_MEMORY_SCOPE_AGENT);
      __hip_atomic_store(dst + 1,
                         tg | (unsigned long long)pk2(hvP[2], hvP[3]),
                         __ATOMIC_RELAXED, __HIP_MEMORY_SCOPE_AGENT);
      // forbid the compiler from sinking these stores past any later spin loop
      asm volatile("" ::: "memory");
    }
    // ---- own half -> LDS, barrier, own fragments, head-own + next C-init/MFMA
    const int buf = (int)(wt & 1u);
    *(ushort4*)&h_lds[buf][lo * 136 + w * 16 + hi * 4] =
        (ushort4){(unsigned short)hb[0], (unsigned short)hb[1],
                  (unsigned short)hb[2], (unsigned short)hb[3]};
    __syncthreads();
    if (t < TSTEPS - 1) {
#pragma unroll
      for (int g = 0; g < 4; ++g) {
        acc[g][0] = bf2f(gcons[g].x); acc[g][1] = bf2f(gcons[g].y);
        acc[g][2] = bf2f(gcons[g].z); acc[g][3] = bf2f(gcons[g].w);
      }
    }
    hacc = (f32x4){0.f, 0.f, 0.f, 0.f};
#pragma unroll
    for (int kk = 0; kk < 4; ++kk) {
      bf16x8 oa = *(const bf16x8*)&h_lds[buf][lo * 136 + kk * 32 + hi * 8];
      hacc = __builtin_amdgcn_mfma_f32_16x16x32_bf16(wefO[kk], oa, hacc, 0, 0, 0);
      if (t < TSTEPS - 1) {
        acc[0] = __builtin_amdgcn_mfma_f32_16x16x32_bf16(wfO[0][kk], oa, acc[0], 0, 0, 0);
        acc[1] = __builtin_amdgcn_mfma_f32_16x16x32_bf16(wfO[1][kk], oa, acc[1], 0, 0, 0);
        acc[2] = __builtin_amdgcn_mfma_f32_16x16x32_bf16(wfO[2][kk], oa, acc[2], 0, 0, 0);
        acc[3] = __builtin_amdgcn_mfma_f32_16x16x32_bf16(wfO[3][kk], oa, acc[3], 0, 0, 0);
      }
    }
  };
  for (int t = 0; t < TSTEPS; t += 2) {
    step(t, gOdd, gEven);       // consume gx(t+1) [odd], issue gx(t+2) [even]
    step(t + 1, gEven, gOdd);   // consume gx(t+2) [even], issue gx(t+3) [odd]
  }
  // ---- epilogue: head for h(512) (poll tag 512, parity 0), outputs
  {
    const unsigned long long* src =
        hx + ((size_t)(0 * 8 + pslot) * 16 + lo) * 64 + hi * 4;
    unsigned long long v[16];
    unsigned mism;
    const unsigned tagv = (unsigned)TSTEPS;
    do {
      mism = 0u;
#pragma unroll
      for (int kk = 0; kk < 4; ++kk)
#pragma unroll
        for (int q = 0; q < 4; ++q)
          v[kk * 4 + q] = __hip_atomic_load(src + kk * 16 + q, __ATOMIC_RELAXED,
                                            __HIP_MEMORY_SCOPE_AGENT);
#pragma unroll
      for (int i = 0; i < 16; ++i)
        mism |= ((unsigned)(v[i] >> 32)) ^ tagv;
    } while (__any(mism != 0u));
#pragma unroll
    for (int kk = 0; kk < 4; ++kk) {
      uint4 dv = {(unsigned)v[kk * 4 + 0], (unsigned)v[kk * 4 + 1],
                  (unsigned)v[kk * 4 + 2], (unsigned)v[kk * 4 + 3]};
      bf16x8 pa = __builtin_bit_cast(bf16x8, dv);
      hacc = __builtin_amdgcn_mfma_f32_16x16x32_bf16(wefP[kk], pa, hacc, 0, 0, 0);
    }
    sig_acc += fsig(hacc[0] + c0);
  }
  if (w == 0 && hi == 0 && half == 0) out[b0 + lo] = sig_acc * (1.f / 512.f);
  {
    const int u0 = half * 128 + w * 16 + hi * 4;
    float4 ho = {hvP[0], hvP[1], hvP[2], hvP[3]};
    float4 co = {c[0], c[1], c[2], c[3]};
    *(float4*)&out[64 + (size_t)(b0 + lo) * HDIM + u0] = ho;
    *(float4*)&out[64 + BATCH * HDIM + (size_t)(b0 + lo) * HDIM + u0] = co;
  }
}

// ---------------- K3: w_eff[k] = sum_j Wf[j]*Wm[j][k]; weff[256] = bm.Wf+bf --
__global__ __launch_bounds__(256) void k_weff(const float* __restrict__ Wm,
                                              const float* __restrict__ bm,
                                              const float* __restrict__ Wf,
                                              const float* __restrict__ bfb,
                                              float* __restrict__ weff) {
  const int k = threadIdx.x;
  __shared__ float red[256];
  float acc = 0.f;
#pragma unroll 8
  for (int jj = 0; jj < 256; ++jj) acc += Wf[jj] * Wm[jj * 256 + k];
  weff[k] = acc;
  red[k] = bm[k] * Wf[k];
  __syncthreads();
  for (int s = 128; s > 0; s >>= 1) {
    if (k < s) red[k] += red[k + s];
    __syncthreads();
  }
  if (k == 0) weff[256] = red[0] + bfb[0];
}

extern "C" void kernel_launch(void* const* d_in, const int* in_sizes, int n_in,
                              void* d_out, int out_size, void* d_ws, size_t ws_size,
                              hipStream_t stream) {
  (void)in_sizes; (void)n_in; (void)out_size; (void)ws_size;
  const int* x = (const int*)d_in[0];
  const float* emb = (const float*)d_in[1];
  const float* Wih = (const float*)d_in[2];
  const float* Whh = (const float*)d_in[3];
  const float* bih = (const float*)d_in[4];
  const float* bhh = (const float*)d_in[5];
  const float* Wm  = (const float*)d_in[6];
  const float* bm  = (const float*)d_in[7];
  const float* Wf  = (const float*)d_in[8];
  const float* bf  = (const float*)d_in[9];
  float* out = (float*)d_out;
  char* ws = (char*)d_ws;
  const size_t gx_bytes = (size_t)TSTEPS * BATCH * G4H * 2;  // 67,108,864
  const size_t hx_bytes = (size_t)2 * 8 * 16 * 64 * 8;       // 131,072
  unsigned short* gx = (unsigned short*)ws;
  unsigned long long* hx = (unsigned long long*)(ws + gx_bytes);
  float* weff = (float*)(ws + gx_bytes + hx_bytes);
  hipMemsetAsync(hx, 0, hx_bytes, stream);  // tags start at 0 every launch
  k_gx<<<dim3(512, 16), 256, 0, stream>>>(x, emb, Wih, bih, bhh, gx);
  k_weff<<<1, 256, 0, stream>>>(Wm, bm, Wf, bf, weff);
  k_rec<<<8, 512, 0, stream>>>(gx, Whh, weff, hx, out);
}

// Round 9
// 1197.408 us; speedup vs baseline: 5.9293x; 2.4311x over previous
//
#include <hip/hip_runtime.h>

// SentimentLSTM: B=64, T=512, E=128, H=256, V=100000, O=1
// outputs: sig_out[64], hT[1,64,256], cT[1,64,256] -> 32832 f32
//
// k_rec (R4-proven structure + 3 deltas): 8 blocks = 4 groups x 2 halves.
//   block (grp, half): batches grp*16..+15, units half*128..+127, all gates.
//   W slice (512 rows x 256) bf16 = 128 VGPRs, static-indexed wf[4][8].
//   Wave w owns units half*128 + w*16 + lo -> cell update lane-local.
//   Pairwise tagged exchange (u64 = {2 bf16, tag}), 2-u64/thread poll.
//   Deltas vs R4: (1) gx prefetch issued AFTER poll detect (only 2 stores
//   ahead of poll in vmem queue); (2) output head fused from h_lds (hs and
//   k_sig deleted); (3) hT/cT written from registers in epilogue.
//
// ws layout:
//   gx3  bf16 [T][8 slot][8 w][64 lane][16]  67,108,864 B  (lane-major)
//   hx   u64  [2 par][8 slot][1024]             131,072 B
//   weff f32  [257]                               1,028 B

#define BATCH 64
#define TSTEPS 512
#define EDIM 128
#define HDIM 256
#define G4H 1024

typedef short bf16x8 __attribute__((ext_vector_type(8)));
typedef short bf16x4 __attribute__((ext_vector_type(4)));
typedef float f32x4 __attribute__((ext_vector_type(4)));

__device__ __forceinline__ unsigned short f2bf(float f) {
  unsigned u = __builtin_bit_cast(unsigned, f);
  return (unsigned short)((u + 0x7fffu + ((u >> 16) & 1u)) >> 16);
}
__device__ __forceinline__ float bf2f(unsigned short h) {
  unsigned u = ((unsigned)h) << 16;
  return __builtin_bit_cast(float, u);
}
__device__ __forceinline__ unsigned pk2(float a, float b) {
  return (unsigned)f2bf(a) | ((unsigned)f2bf(b) << 16);
}
__device__ __forceinline__ float fsig(float x) {
  return __builtin_amdgcn_rcpf(1.f + __expf(-x));
}
__device__ __forceinline__ float ftanh(float x) {
  return 1.f - 2.f * __builtin_amdgcn_rcpf(__expf(2.f * x) + 1.f);
}
__device__ __forceinline__ bf16x8 ldfrag(const unsigned short* p) {
  bf16x4 a = *(const bf16x4*)p;
  bf16x4 b = *(const bf16x4*)(p + 16);
  return __builtin_shufflevector(a, b, 0, 1, 2, 3, 4, 5, 6, 7);
}
__device__ __forceinline__ bf16x8 pack8(float4 v0, float4 v1) {
  bf16x8 f;
  f[0] = (short)f2bf(v0.x); f[1] = (short)f2bf(v0.y);
  f[2] = (short)f2bf(v0.z); f[3] = (short)f2bf(v0.w);
  f[4] = (short)f2bf(v1.x); f[5] = (short)f2bf(v1.y);
  f[6] = (short)f2bf(v1.z); f[7] = (short)f2bf(v1.w);
  return f;
}

// ---------------- K1: gx3[lane-major layout] = emb[x] @ W_ih^T + b_ih ------
__global__ __launch_bounds__(256) void k_gx(const int* __restrict__ x,
                                            const float* __restrict__ emb,
                                            const float* __restrict__ Wih,
                                            const float* __restrict__ bih,
                                            unsigned short* __restrict__ gx3) {
  const int t = blockIdx.x;
  const int g0 = blockIdx.y * 64;
  const int tid = threadIdx.x;
  __shared__ unsigned short Al[64 * 136];
  __shared__ unsigned short Bl[64 * 136];
  __shared__ int tok[64];
  if (tid < 64) tok[tid] = x[tid * TSTEPS + t];
  __syncthreads();
  {
    const int r = tid >> 2, c0 = (tid & 3) * 32;
    const float* asrc = emb + (size_t)tok[r] * EDIM + c0;
    const float* bsrc = Wih + (size_t)(g0 + r) * EDIM + c0;
#pragma unroll
    for (int s = 0; s < 32; s += 8) {
      float4 a0 = *(const float4*)(asrc + s);
      float4 a1 = *(const float4*)(asrc + s + 4);
      uint4 pa = {pk2(a0.x, a0.y), pk2(a0.z, a0.w), pk2(a1.x, a1.y), pk2(a1.z, a1.w)};
      *(uint4*)&Al[r * 136 + c0 + s] = pa;
      float4 b0 = *(const float4*)(bsrc + s);
      float4 b1 = *(const float4*)(bsrc + s + 4);
      uint4 pb = {pk2(b0.x, b0.y), pk2(b0.z, b0.w), pk2(b1.x, b1.y), pk2(b1.z, b1.w)};
      *(uint4*)&Bl[r * 136 + c0 + s] = pb;
    }
  }
  __syncthreads();
  const int lane = tid & 63, w = tid >> 6;
  const int lo = lane & 15, hi = lane >> 4;
  const int mb = (w & 1) * 32, nb = (w >> 1) * 32;
  f32x4 acc[2][2];
#pragma unroll
  for (int jj = 0; jj < 2; ++jj) {
    float bv = bih[g0 + nb + jj * 16 + lo];
    acc[0][jj] = (f32x4){bv, bv, bv, bv};
    acc[1][jj] = acc[0][jj];
  }
#pragma unroll
  for (int kk = 0; kk < 4; ++kk) {
    bf16x8 af0 = ldfrag(&Al[(mb + lo) * 136 + kk * 32 + hi * 4]);
    bf16x8 af1 = ldfrag(&Al[(mb + 16 + lo) * 136 + kk * 32 + hi * 4]);
    bf16x8 bf0 = ldfrag(&Bl[(nb + lo) * 136 + kk * 32 + hi * 4]);
    bf16x8 bf1 = ldfrag(&Bl[(nb + 16 + lo) * 136 + kk * 32 + hi * 4]);
    acc[0][0] = __builtin_amdgcn_mfma_f32_16x16x32_bf16(af0, bf0, acc[0][0], 0, 0, 0);
    acc[0][1] = __builtin_amdgcn_mfma_f32_16x16x32_bf16(af0, bf1, acc[0][1], 0, 0, 0);
    acc[1][0] = __builtin_amdgcn_mfma_f32_16x16x32_bf16(af1, bf0, acc[1][0], 0, 0, 0);
    acc[1][1] = __builtin_amdgcn_mfma_f32_16x16x32_bf16(af1, bf1, acc[1][1], 0, 0, 0);
  }
  // packed u64 stores: 4 contiguous bf16 (g*4 + r, r=0..3) per (i,jj)
#pragma unroll
  for (int i = 0; i < 2; ++i)
#pragma unroll
    for (int jj = 0; jj < 2; ++jj) {
      int grp = (w & 1) * 2 + i;              // batch group (m>>4)
      int col = g0 + nb + jj * 16 + lo;
      int g = col >> 8, jc = col & 255;
      int halfb = jc >> 7, wv = (jc >> 4) & 7, lov = jc & 15;
      size_t base = (((size_t)(t * 8 + grp * 2 + halfb) * 8 + wv) * 64 +
                     (hi * 16 + lov)) * 16 + g * 4;
      unsigned long long val =
          (unsigned long long)pk2(acc[i][jj][0], acc[i][jj][1]) |
          ((unsigned long long)pk2(acc[i][jj][2], acc[i][jj][3]) << 32);
      *(unsigned long long*)&gx3[base] = val;
    }
}

// ---------------- K2: recurrence + fused head (R4 structure) ----------------
__global__ __launch_bounds__(512, 2) void k_rec(const unsigned short* __restrict__ gx3,
                                                const float* __restrict__ Whh,
                                                const float* __restrict__ bhh,
                                                const float* __restrict__ weff,
                                                unsigned long long* __restrict__ hx,
                                                float* __restrict__ out) {
  const int tid = threadIdx.x;
  const int bp = blockIdx.x;             // 0..7
  const int grp = bp >> 1, half = bp & 1;
  const int b0 = grp * 16;
  const int lane = tid & 63, w = tid >> 6;
  const int lo = lane & 15, hi = lane >> 4;
  const int j = half * 128 + w * 16 + lo;  // this lane's unit (0..255)
  // h_lds k-major: [granule = k>>3][batch][8 elems], stride 136 u16/granule
  __shared__ unsigned short h_lds[2][32 * 136];
  // persistent W: wf[g][kk][e] = Whh[g*256+j][kk*32 + hi*8 + e]  (bf16)
  bf16x8 wf[4][8];
  float bhv[4];
#pragma unroll
  for (int g = 0; g < 4; ++g) {
    const float* wr = Whh + (size_t)(g * 256 + j) * HDIM;
    bhv[g] = bhh[g * 256 + j];
#pragma unroll
    for (int kk = 0; kk < 8; ++kk) {
      const float* p = wr + kk * 32 + hi * 8;
      wf[g][kk] = pack8(*(const float4*)p, *(const float4*)(p + 4));
    }
  }
  // fused-head roles: thread = (batch hb_b, granule hb_g); weff slice in regs
  const int hb_b = tid >> 5, hb_g = tid & 31;
  float wv8[8];
#pragma unroll
  for (int e = 0; e < 8; ++e) wv8[e] = weff[hb_g * 8 + e];
  const float c0 = weff[256];
  float sig_acc = 0.f;
  // zero h_lds[0]
  for (int i = tid; i < 32 * 136 / 2; i += 512) ((unsigned*)h_lds[0])[i] = 0u;
  // gx base for this lane; per-t stride = 65536 u16 (=B*4H)
  const unsigned short* gp = gx3 + (((size_t)bp * 8 + w) * 64 + lane) * 16;
  unsigned gwA[8], gwB[8];
  {
    uint4 a = *(const uint4*)(gp);
    uint4 b = *(const uint4*)(gp + 8);
    gwA[0] = a.x; gwA[1] = a.y; gwA[2] = a.z; gwA[3] = a.w;
    gwA[4] = b.x; gwA[5] = b.y; gwA[6] = b.z; gwA[7] = b.w;
    uint4 c2 = *(const uint4*)(gp + 65536);
    uint4 d2 = *(const uint4*)(gp + 65536 + 8);
    gwB[0] = c2.x; gwB[1] = c2.y; gwB[2] = c2.z; gwB[3] = c2.w;
    gwB[4] = d2.x; gwB[5] = d2.y; gwB[6] = d2.z; gwB[7] = d2.w;
  }
  float c[4] = {0.f, 0.f, 0.f, 0.f};
  float hv[4];
  const int ob = (j >> 3) * 136 + (j & 7);           // own-unit LDS offset
  const int jp = ((half ^ 1) * 128) + ((tid >> 6) << 4) + (tid & 15);
  const int hip = (tid >> 4) & 3;
  const int pb = (jp >> 3) * 136 + (jp & 7);         // partner-unit LDS offset
  __syncthreads();
  auto step = [&](int t, unsigned (&G)[8]) {
    const int cur = t & 1, nxt = cur ^ 1;
    const unsigned wt = (unsigned)(t + 1);
    // C init = gx + b_hh  (C map: row=batch=hi*4+r, col=lane's unit)
    f32x4 acc[4];
#pragma unroll
    for (int g = 0; g < 4; ++g)
#pragma unroll
      for (int r = 0; r < 4; ++r) {
        unsigned word = G[g * 2 + (r >> 1)];
        unsigned short v = (r & 1) ? (unsigned short)(word >> 16) : (unsigned short)word;
        acc[g][r] = bf2f(v) + bhv[g];
      }
    // h @ W^T : A = h fragment (batch lo, k = kk*32+hi*8+e matches wf recipe)
#pragma unroll
    for (int kk = 0; kk < 8; ++kk) {
      bf16x8 a = *(const bf16x8*)&h_lds[cur][(kk * 4 + hi) * 136 + lo * 8];
      acc[0] = __builtin_amdgcn_mfma_f32_16x16x32_bf16(a, wf[0][kk], acc[0], 0, 0, 0);
      acc[1] = __builtin_amdgcn_mfma_f32_16x16x32_bf16(a, wf[1][kk], acc[1], 0, 0, 0);
      acc[2] = __builtin_amdgcn_mfma_f32_16x16x32_bf16(a, wf[2][kk], acc[2], 0, 0, 0);
      acc[3] = __builtin_amdgcn_mfma_f32_16x16x32_bf16(a, wf[3][kk], acc[3], 0, 0, 0);
    }
    // lane-local cell update: lane holds i,f,g,o for (b=b0+hi*4+r, u=j)
    unsigned short hbf[4];
#pragma unroll
    for (int r = 0; r < 4; ++r) {
      float iv = fsig(acc[0][r]), fv = fsig(acc[1][r]);
      float gv = ftanh(acc[2][r]), ov = fsig(acc[3][r]);
      c[r] = fv * c[r] + iv * gv;
      hv[r] = ov * ftanh(c[r]);
      hbf[r] = f2bf(hv[r]);
    }
    // tagged exchange: 2 u64 stores — the ONLY vmem ahead of the poll
    const int par = (int)(wt & 1u);
    {
      const unsigned long long tg = ((unsigned long long)wt) << 32;
      unsigned long long* dst = &hx[((size_t)(par * 8 + bp)) * 1024 + w * 128 + lane * 2];
      __hip_atomic_store(&dst[0], tg | (unsigned long long)pk2(hv[0], hv[1]),
                         __ATOMIC_RELAXED, __HIP_MEMORY_SCOPE_AGENT);
      __hip_atomic_store(&dst[1], tg | (unsigned long long)pk2(hv[2], hv[3]),
                         __ATOMIC_RELAXED, __HIP_MEMORY_SCOPE_AGENT);
      asm volatile("" ::: "memory");  // don't sink stores past the spin loop
    }
    // own half into h_lds[nxt] (k-major)
#pragma unroll
    for (int r = 0; r < 4; ++r) h_lds[nxt][ob + (hi * 4 + r) * 8] = hbf[r];
    // poll partner: exactly 2 u64 loads per thread
    unsigned long long v0, v1;
    {
      unsigned long long* src = &hx[((size_t)(par * 8 + (bp ^ 1))) * 1024 + tid * 2];
      do {
        v0 = __hip_atomic_load(&src[0], __ATOMIC_RELAXED, __HIP_MEMORY_SCOPE_AGENT);
        v1 = __hip_atomic_load(&src[1], __ATOMIC_RELAXED, __HIP_MEMORY_SCOPE_AGENT);
      } while ((unsigned)(v0 >> 32) != wt || (unsigned)(v1 >> 32) != wt);
    }
    // issue gx(t+2) NOW (retires ~1.5 steps before its consumption; never
    // sits in the vmem queue ahead of this step's poll)
    if (t + 2 < TSTEPS) {
      const unsigned short* q = gp + (size_t)(t + 2) * 65536;
      uint4 a = *(const uint4*)(q);
      uint4 b = *(const uint4*)(q + 8);
      G[0] = a.x; G[1] = a.y; G[2] = a.z; G[3] = a.w;
      G[4] = b.x; G[5] = b.y; G[6] = b.z; G[7] = b.w;
    }
    // partner half into h_lds[nxt]
    h_lds[nxt][pb + (hip * 4 + 0) * 8] = (unsigned short)v0;
    h_lds[nxt][pb + (hip * 4 + 1) * 8] = (unsigned short)(v0 >> 16);
    h_lds[nxt][pb + (hip * 4 + 2) * 8] = (unsigned short)v1;
    h_lds[nxt][pb + (hip * 4 + 3) * 8] = (unsigned short)(v1 >> 16);
    __syncthreads();
    // fused head: thread (hb_b, hb_g) dots 8 units of h(t+1) with weff
    {
      bf16x8 hh = *(const bf16x8*)&h_lds[nxt][hb_g * 136 + hb_b * 8];
      float s = 0.f;
#pragma unroll
      for (int e = 0; e < 8; ++e) s += bf2f((unsigned short)hh[e]) * wv8[e];
      s += __shfl_xor(s, 1);  s += __shfl_xor(s, 2);  s += __shfl_xor(s, 4);
      s += __shfl_xor(s, 8);  s += __shfl_xor(s, 16);
      sig_acc += fsig(s + c0);
    }
  };
  for (int t = 0; t < TSTEPS; t += 2) {
    step(t, gwA);       // consume gx(t),   re-issue gx(t+2)
    step(t + 1, gwB);   // consume gx(t+1), re-issue gx(t+3)
  }
  // epilogue: sig mean (half 0 only; both halves compute identical sums),
  // hT/cT from registers
  if (half == 0 && hb_g == 0) out[b0 + hb_b] = sig_acc * (1.f / 512.f);
#pragma unroll
  for (int r = 0; r < 4; ++r) {
    const int b = b0 + hi * 4 + r;
    out[64 + b * HDIM + j] = hv[r];
    out[64 + BATCH * HDIM + b * HDIM + j] = c[r];
  }
}

// ---------------- K3: w_eff[k] = sum_j Wf[j]*Wm[j][k]; weff[256] = bm.Wf+bf --
__global__ __launch_bounds__(256) void k_weff(const float* __restrict__ Wm,
                                              const float* __restrict__ bm,
                                              const float* __restrict__ Wf,
                                              const float* __restrict__ bfb,
                                              float* __restrict__ weff) {
  const int k = threadIdx.x;
  __shared__ float red[256];
  float acc = 0.f;
#pragma unroll 8
  for (int jj = 0; jj < 256; ++jj) acc += Wf[jj] * Wm[jj * 256 + k];
  weff[k] = acc;
  red[k] = bm[k] * Wf[k];
  __syncthreads();
  for (int s = 128; s > 0; s >>= 1) {
    if (k < s) red[k] += red[k + s];
    __syncthreads();
  }
  if (k == 0) weff[256] = red[0] + bfb[0];
}

extern "C" void kernel_launch(void* const* d_in, const int* in_sizes, int n_in,
                              void* d_out, int out_size, void* d_ws, size_t ws_size,
                              hipStream_t stream) {
  (void)in_sizes; (void)n_in; (void)out_size; (void)ws_size;
  const int* x = (const int*)d_in[0];
  const float* emb = (const float*)d_in[1];
  const float* Wih = (const float*)d_in[2];
  const float* Whh = (const float*)d_in[3];
  const float* bih = (const float*)d_in[4];
  const float* bhh = (const float*)d_in[5];
  const float* Wm  = (const float*)d_in[6];
  const float* bm  = (const float*)d_in[7];
  const float* Wf  = (const float*)d_in[8];
  const float* bf  = (const float*)d_in[9];
  float* out = (float*)d_out;
  char* ws = (char*)d_ws;
  const size_t gx_bytes = (size_t)TSTEPS * BATCH * G4H * 2;  // 67,108,864
  const size_t hx_bytes = (size_t)2 * 8 * 1024 * 8;          // 131,072
  unsigned short* gx3 = (unsigned short*)ws;
  unsigned long long* hx = (unsigned long long*)(ws + gx_bytes);
  float* weff = (float*)(ws + gx_bytes + hx_bytes);
  hipMemsetAsync(hx, 0, hx_bytes, stream);  // tags start at 0 every launch
  k_gx<<<dim3(512, 16), 256, 0, stream>>>(x, emb, Wih, bih, gx3);
  k_weff<<<1, 256, 0, stream>>>(Wm, bm, Wf, bf, weff);
  k_rec<<<8, 512, 0, stream>>>(gx3, Whh, bhh, weff, hx, out);
}

// Round 10
// 1034.122 us; speedup vs baseline: 6.8655x; 1.1579x over previous
//
#include <hip/hip_runtime.h>

// SentimentLSTM: B=64, T=512, E=128, H=256, V=100000, O=1
// outputs: sig_out[64], hT[1,64,256], cT[1,64,256] -> 32832 f32
//
// k_rec: 8 blocks = 4 groups x 2 halves (R9 structure + split-K pipeline).
//   Per step: partner-half MFMA -> update -> tagged store -> own LDS write
//   -> B1 -> [SHADOW: C-init(t+1) + own-half MFMA(t+1) + head(t)] -> 2-deep
//   pipelined poll -> partner LDS write -> B2.  The shadow work executes
//   while the exchange store propagates to the coherence point.
//
// ws layout:
//   gx3  bf16 [T][8 slot][8 w][64 lane][16]  67,108,864 B  (lane-major)
//   hx   u64  [2 par][8 slot][1024]             131,072 B
//   weff f32  [257]                               1,028 B

#define BATCH 64
#define TSTEPS 512
#define EDIM 128
#define HDIM 256
#define G4H 1024

typedef short bf16x8 __attribute__((ext_vector_type(8)));
typedef short bf16x4 __attribute__((ext_vector_type(4)));
typedef float f32x4 __attribute__((ext_vector_type(4)));

__device__ __forceinline__ unsigned short f2bf(float f) {
  unsigned u = __builtin_bit_cast(unsigned, f);
  return (unsigned short)((u + 0x7fffu + ((u >> 16) & 1u)) >> 16);
}
__device__ __forceinline__ float bf2f(unsigned short h) {
  unsigned u = ((unsigned)h) << 16;
  return __builtin_bit_cast(float, u);
}
__device__ __forceinline__ unsigned pk2(float a, float b) {
  return (unsigned)f2bf(a) | ((unsigned)f2bf(b) << 16);
}
__device__ __forceinline__ float fsig(float x) {
  return __builtin_amdgcn_rcpf(1.f + __expf(-x));
}
__device__ __forceinline__ float ftanh(float x) {
  return 1.f - 2.f * __builtin_amdgcn_rcpf(__expf(2.f * x) + 1.f);
}
__device__ __forceinline__ bf16x8 ldfrag(const unsigned short* p) {
  bf16x4 a = *(const bf16x4*)p;
  bf16x4 b = *(const bf16x4*)(p + 16);
  return __builtin_shufflevector(a, b, 0, 1, 2, 3, 4, 5, 6, 7);
}
__device__ __forceinline__ bf16x8 pack8(float4 v0, float4 v1) {
  bf16x8 f;
  f[0] = (short)f2bf(v0.x); f[1] = (short)f2bf(v0.y);
  f[2] = (short)f2bf(v0.z); f[3] = (short)f2bf(v0.w);
  f[4] = (short)f2bf(v1.x); f[5] = (short)f2bf(v1.y);
  f[6] = (short)f2bf(v1.z); f[7] = (short)f2bf(v1.w);
  return f;
}

// ---------------- K1: gx3[lane-major layout] = emb[x] @ W_ih^T + b_ih ------
__global__ __launch_bounds__(256) void k_gx(const int* __restrict__ x,
                                            const float* __restrict__ emb,
                                            const float* __restrict__ Wih,
                                            const float* __restrict__ bih,
                                            unsigned short* __restrict__ gx3) {
  const int t = blockIdx.x;
  const int g0 = blockIdx.y * 64;
  const int tid = threadIdx.x;
  __shared__ unsigned short Al[64 * 136];
  __shared__ unsigned short Bl[64 * 136];
  __shared__ int tok[64];
  if (tid < 64) tok[tid] = x[tid * TSTEPS + t];
  __syncthreads();
  {
    const int r = tid >> 2, c0 = (tid & 3) * 32;
    const float* asrc = emb + (size_t)tok[r] * EDIM + c0;
    const float* bsrc = Wih + (size_t)(g0 + r) * EDIM + c0;
#pragma unroll
    for (int s = 0; s < 32; s += 8) {
      float4 a0 = *(const float4*)(asrc + s);
      float4 a1 = *(const float4*)(asrc + s + 4);
      uint4 pa = {pk2(a0.x, a0.y), pk2(a0.z, a0.w), pk2(a1.x, a1.y), pk2(a1.z, a1.w)};
      *(uint4*)&Al[r * 136 + c0 + s] = pa;
      float4 b0 = *(const float4*)(bsrc + s);
      float4 b1 = *(const float4*)(bsrc + s + 4);
      uint4 pb = {pk2(b0.x, b0.y), pk2(b0.z, b0.w), pk2(b1.x, b1.y), pk2(b1.z, b1.w)};
      *(uint4*)&Bl[r * 136 + c0 + s] = pb;
    }
  }
  __syncthreads();
  const int lane = tid & 63, w = tid >> 6;
  const int lo = lane & 15, hi = lane >> 4;
  const int mb = (w & 1) * 32, nb = (w >> 1) * 32;
  f32x4 acc[2][2];
#pragma unroll
  for (int jj = 0; jj < 2; ++jj) {
    float bv = bih[g0 + nb + jj * 16 + lo];
    acc[0][jj] = (f32x4){bv, bv, bv, bv};
    acc[1][jj] = acc[0][jj];
  }
#pragma unroll
  for (int kk = 0; kk < 4; ++kk) {
    bf16x8 af0 = ldfrag(&Al[(mb + lo) * 136 + kk * 32 + hi * 4]);
    bf16x8 af1 = ldfrag(&Al[(mb + 16 + lo) * 136 + kk * 32 + hi * 4]);
    bf16x8 bf0 = ldfrag(&Bl[(nb + lo) * 136 + kk * 32 + hi * 4]);
    bf16x8 bf1 = ldfrag(&Bl[(nb + 16 + lo) * 136 + kk * 32 + hi * 4]);
    acc[0][0] = __builtin_amdgcn_mfma_f32_16x16x32_bf16(af0, bf0, acc[0][0], 0, 0, 0);
    acc[0][1] = __builtin_amdgcn_mfma_f32_16x16x32_bf16(af0, bf1, acc[0][1], 0, 0, 0);
    acc[1][0] = __builtin_amdgcn_mfma_f32_16x16x32_bf16(af1, bf0, acc[1][0], 0, 0, 0);
    acc[1][1] = __builtin_amdgcn_mfma_f32_16x16x32_bf16(af1, bf1, acc[1][1], 0, 0, 0);
  }
#pragma unroll
  for (int i = 0; i < 2; ++i)
#pragma unroll
    for (int jj = 0; jj < 2; ++jj) {
      int grp = (w & 1) * 2 + i;
      int col = g0 + nb + jj * 16 + lo;
      int g = col >> 8, jc = col & 255;
      int halfb = jc >> 7, wv = (jc >> 4) & 7, lov = jc & 15;
      size_t base = (((size_t)(t * 8 + grp * 2 + halfb) * 8 + wv) * 64 +
                     (hi * 16 + lov)) * 16 + g * 4;
      unsigned long long val =
          (unsigned long long)pk2(acc[i][jj][0], acc[i][jj][1]) |
          ((unsigned long long)pk2(acc[i][jj][2], acc[i][jj][3]) << 32);
      *(unsigned long long*)&gx3[base] = val;
    }
}

// ---------------- K2: recurrence, split-K pipelined -------------------------
__global__ __launch_bounds__(512, 2) void k_rec(const unsigned short* __restrict__ gx3,
                                                const float* __restrict__ Whh,
                                                const float* __restrict__ bhh,
                                                const float* __restrict__ weff,
                                                unsigned long long* __restrict__ hx,
                                                float* __restrict__ out) {
  const int tid = threadIdx.x;
  const int bp = blockIdx.x;             // 0..7
  const int grp = bp >> 1, half = bp & 1;
  const int b0 = grp * 16;
  const int lane = tid & 63, w = tid >> 6;
  const int lo = lane & 15, hi = lane >> 4;
  const int j = half * 128 + w * 16 + lo;
  __shared__ unsigned short h_lds[2][32 * 136];  // k-major [granule][batch][8]
  bf16x8 wf[4][8];
  float bhv[4];
#pragma unroll
  for (int g = 0; g < 4; ++g) {
    const float* wr = Whh + (size_t)(g * 256 + j) * HDIM;
    bhv[g] = bhh[g * 256 + j];
#pragma unroll
    for (int kk = 0; kk < 8; ++kk) {
      const float* p = wr + kk * 32 + hi * 8;
      wf[g][kk] = pack8(*(const float4*)p, *(const float4*)(p + 4));
    }
  }
  const int hb_b = tid >> 5, hb_g = tid & 31;
  float wv8[8];
#pragma unroll
  for (int e = 0; e < 8; ++e) wv8[e] = weff[hb_g * 8 + e];
  const float c0 = weff[256];
  float sig_acc = 0.f;
  for (int i = tid; i < 32 * 136 / 2; i += 512) ((unsigned*)h_lds[0])[i] = 0u;
  const unsigned short* gp = gx3 + (((size_t)bp * 8 + w) * 64 + lane) * 16;
  unsigned gwE[8], gwO[8];
  {
    uint4 a = *(const uint4*)(gp);
    uint4 b = *(const uint4*)(gp + 8);
    gwE[0] = a.x; gwE[1] = a.y; gwE[2] = a.z; gwE[3] = a.w;
    gwE[4] = b.x; gwE[5] = b.y; gwE[6] = b.z; gwE[7] = b.w;
    uint4 c2 = *(const uint4*)(gp + 65536);
    uint4 d2 = *(const uint4*)(gp + 65536 + 8);
    gwO[0] = c2.x; gwO[1] = c2.y; gwO[2] = c2.z; gwO[3] = c2.w;
    gwO[4] = d2.x; gwO[5] = d2.y; gwO[6] = d2.z; gwO[7] = d2.w;
  }
  float c[4] = {0.f, 0.f, 0.f, 0.f};
  float hv[4];
  f32x4 acc[4];
  const int ob = (j >> 3) * 136 + (j & 7);
  const int jp = ((half ^ 1) * 128) + ((tid >> 6) << 4) + (tid & 15);
  const int hip = (tid >> 4) & 3;
  const int pb = (jp >> 3) * 136 + (jp & 7);
  __syncthreads();

  auto cinit = [&](const unsigned (&G)[8]) {
#pragma unroll
    for (int g = 0; g < 4; ++g)
#pragma unroll
      for (int r = 0; r < 4; ++r) {
        unsigned word = G[g * 2 + (r >> 1)];
        unsigned short v = (r & 1) ? (unsigned short)(word >> 16) : (unsigned short)word;
        acc[g][r] = bf2f(v) + bhv[g];
      }
  };
  auto mfma_own = [&](int buf) {  // own-half K: static kk ranges per half
    if (half == 0) {
#pragma unroll
      for (int kk = 0; kk < 4; ++kk) {
        bf16x8 a = *(const bf16x8*)&h_lds[buf][(kk * 4 + hi) * 136 + lo * 8];
#pragma unroll
        for (int g = 0; g < 4; ++g)
          acc[g] = __builtin_amdgcn_mfma_f32_16x16x32_bf16(a, wf[g][kk], acc[g], 0, 0, 0);
      }
    } else {
#pragma unroll
      for (int kk = 4; kk < 8; ++kk) {
        bf16x8 a = *(const bf16x8*)&h_lds[buf][(kk * 4 + hi) * 136 + lo * 8];
#pragma unroll
        for (int g = 0; g < 4; ++g)
          acc[g] = __builtin_amdgcn_mfma_f32_16x16x32_bf16(a, wf[g][kk], acc[g], 0, 0, 0);
      }
    }
  };
  auto mfma_par = [&](int buf) {  // partner-half K
    if (half == 0) {
#pragma unroll
      for (int kk = 4; kk < 8; ++kk) {
        bf16x8 a = *(const bf16x8*)&h_lds[buf][(kk * 4 + hi) * 136 + lo * 8];
#pragma unroll
        for (int g = 0; g < 4; ++g)
          acc[g] = __builtin_amdgcn_mfma_f32_16x16x32_bf16(a, wf[g][kk], acc[g], 0, 0, 0);
      }
    } else {
#pragma unroll
      for (int kk = 0; kk < 4; ++kk) {
        bf16x8 a = *(const bf16x8*)&h_lds[buf][(kk * 4 + hi) * 136 + lo * 8];
#pragma unroll
        for (int g = 0; g < 4; ++g)
          acc[g] = __builtin_amdgcn_mfma_f32_16x16x32_bf16(a, wf[g][kk], acc[g], 0, 0, 0);
      }
    }
  };
  auto update_store = [&](int t) {  // U(t) + S(t) + own W(t)
    const unsigned wt = (unsigned)(t + 1);
    unsigned short hbf[4];
#pragma unroll
    for (int r = 0; r < 4; ++r) {
      float iv = fsig(acc[0][r]), fv = fsig(acc[1][r]);
      float gv = ftanh(acc[2][r]), ov = fsig(acc[3][r]);
      c[r] = fv * c[r] + iv * gv;
      hv[r] = ov * ftanh(c[r]);
      hbf[r] = f2bf(hv[r]);
    }
    const int par = (int)(wt & 1u);
    unsigned long long* dst = &hx[((size_t)(par * 8 + bp)) * 1024 + w * 128 + lane * 2];
    const unsigned long long tg = ((unsigned long long)wt) << 32;
    __hip_atomic_store(&dst[0], tg | (unsigned long long)pk2(hv[0], hv[1]),
                       __ATOMIC_RELAXED, __HIP_MEMORY_SCOPE_AGENT);
    __hip_atomic_store(&dst[1], tg | (unsigned long long)pk2(hv[2], hv[3]),
                       __ATOMIC_RELAXED, __HIP_MEMORY_SCOPE_AGENT);
    asm volatile("" ::: "memory");
#pragma unroll
    for (int r = 0; r < 4; ++r) h_lds[par][ob + (hi * 4 + r) * 8] = hbf[r];
  };
  auto head = [&](int buf) {
    bf16x8 hh = *(const bf16x8*)&h_lds[buf][hb_g * 136 + hb_b * 8];
    float s = 0.f;
#pragma unroll
    for (int e = 0; e < 8; ++e) s += bf2f((unsigned short)hh[e]) * wv8[e];
    s += __shfl_xor(s, 1);  s += __shfl_xor(s, 2);  s += __shfl_xor(s, 4);
    s += __shfl_xor(s, 8);  s += __shfl_xor(s, 16);
    sig_acc += fsig(s + c0);
  };
  auto gx_issue = [&](int s, unsigned (&G)[8]) {
    const unsigned short* q = gp + (size_t)s * 65536;
    uint4 a = *(const uint4*)(q);
    uint4 b = *(const uint4*)(q + 8);
    G[0] = a.x; G[1] = a.y; G[2] = a.z; G[3] = a.w;
    G[4] = b.x; G[5] = b.y; G[6] = b.z; G[7] = b.w;
  };
  auto poll_write = [&](int t) {  // PL(t+1) + partner W2, 2-deep pipelined
    const unsigned wt = (unsigned)(t + 1);
    const int par = (int)(wt & 1u);
    unsigned long long* src = &hx[((size_t)(par * 8 + (bp ^ 1))) * 1024 + tid * 2];
    unsigned long long a0 = __hip_atomic_load(&src[0], __ATOMIC_RELAXED, __HIP_MEMORY_SCOPE_AGENT);
    unsigned long long a1 = __hip_atomic_load(&src[1], __ATOMIC_RELAXED, __HIP_MEMORY_SCOPE_AGENT);
    unsigned long long b0 = __hip_atomic_load(&src[0], __ATOMIC_RELAXED, __HIP_MEMORY_SCOPE_AGENT);
    unsigned long long b1 = __hip_atomic_load(&src[1], __ATOMIC_RELAXED, __HIP_MEMORY_SCOPE_AGENT);
    unsigned long long v0, v1;
    for (;;) {
      if ((unsigned)(a0 >> 32) == wt && (unsigned)(a1 >> 32) == wt) { v0 = a0; v1 = a1; break; }
      a0 = b0; a1 = b1;
      b0 = __hip_atomic_load(&src[0], __ATOMIC_RELAXED, __HIP_MEMORY_SCOPE_AGENT);
      b1 = __hip_atomic_load(&src[1], __ATOMIC_RELAXED, __HIP_MEMORY_SCOPE_AGENT);
    }
    h_lds[par][pb + (hip * 4 + 0) * 8] = (unsigned short)v0;
    h_lds[par][pb + (hip * 4 + 1) * 8] = (unsigned short)(v0 >> 16);
    h_lds[par][pb + (hip * 4 + 2) * 8] = (unsigned short)v1;
    h_lds[par][pb + (hip * 4 + 3) * 8] = (unsigned short)(v1 >> 16);
  };
  auto body = [&](int t, unsigned (&Gc)[8], unsigned (&Gf)[8]) {
    // entry: acc = gx(t)+bhh+own(h(t)); LDS[t&1] holds full h(t)
    mfma_par(t & 1);                 // complete gates(t)
    update_store(t);                 // h(t+1): store + own LDS
    if (t + 2 < TSTEPS) gx_issue(t + 2, Gf);
    __syncthreads();                 // B1: own writes visible
    if (t < TSTEPS - 1) {
      cinit(Gc);                     // gx(t+1)
      mfma_own((t + 1) & 1);         // own-half of step t+1 (shadow)
    }
    head(t & 1);                     // head of h(t) (shadow)
    poll_write(t);                   // partner h(t+1) -> LDS
    __syncthreads();                 // B2
  };

  // prologue: t=0 (h(0)=0 -> gates = gx(0)+bhh, no MFMA)
  cinit(gwE);
  update_store(0);
  gx_issue(2, gwE);
  __syncthreads();                   // B1
  cinit(gwO);
  mfma_own(1);
  poll_write(0);
  __syncthreads();                   // B2
  // main: t = 1..510 paired
  for (int t = 1; t + 1 < TSTEPS - 1; t += 2) {
    body(t, gwE, gwO);
    body(t + 1, gwO, gwE);
  }
  body(TSTEPS - 1, gwE, gwO);        // t=511 (no cinit/own/gx)
  head(0);                           // head of h(512) (buf 0)
  if (half == 0 && hb_g == 0) out[b0 + hb_b] = sig_acc * (1.f / 512.f);
#pragma unroll
  for (int r = 0; r < 4; ++r) {
    const int b = b0 + hi * 4 + r;
    out[64 + b * HDIM + j] = hv[r];
    out[64 + BATCH * HDIM + b * HDIM + j] = c[r];
  }
}

// ---------------- K3: w_eff[k] = sum_j Wf[j]*Wm[j][k]; weff[256] = bm.Wf+bf --
__global__ __launch_bounds__(256) void k_weff(const float* __restrict__ Wm,
                                              const float* __restrict__ bm,
                                              const float* __restrict__ Wf,
                                              const float* __restrict__ bfb,
                                              float* __restrict__ weff) {
  const int k = threadIdx.x;
  __shared__ float red[256];
  float acc = 0.f;
#pragma unroll 8
  for (int jj = 0; jj < 256; ++jj) acc += Wf[jj] * Wm[jj * 256 + k];
  weff[k] = acc;
  red[k] = bm[k] * Wf[k];
  __syncthreads();
  for (int s = 128; s > 0; s >>= 1) {
    if (k < s) red[k] += red[k + s];
    __syncthreads();
  }
  if (k == 0) weff[256] = red[0] + bfb[0];
}

extern "C" void kernel_launch(void* const* d_in, const int* in_sizes, int n_in,
                              void* d_out, int out_size, void* d_ws, size_t ws_size,
                              hipStream_t stream) {
  (void)in_sizes; (void)n_in; (void)out_size; (void)ws_size;
  const int* x = (const int*)d_in[0];
  const float* emb = (const float*)d_in[1];
  const float* Wih = (const float*)d_in[2];
  const float* Whh = (const float*)d_in[3];
  const float* bih = (const float*)d_in[4];
  const float* bhh = (const float*)d_in[5];
  const float* Wm  = (const float*)d_in[6];
  const float* bm  = (const float*)d_in[7];
  const float* Wf  = (const float*)d_in[8];
  const float* bf  = (const float*)d_in[9];
  float* out = (float*)d_out;
  char* ws = (char*)d_ws;
  const size_t gx_bytes = (size_t)TSTEPS * BATCH * G4H * 2;  // 67,108,864
  const size_t hx_bytes = (size_t)2 * 8 * 1024 * 8;          // 131,072
  unsigned short* gx3 = (unsigned short*)ws;
  unsigned long long* hx = (unsigned long long*)(ws + gx_bytes);
  float* weff = (float*)(ws + gx_bytes + hx_bytes);
  hipMemsetAsync(hx, 0, hx_bytes, stream);  // tags start at 0 every launch
  k_gx<<<dim3(512, 16), 256, 0, stream>>>(x, emb, Wih, bih, gx3);
  k_weff<<<1, 256, 0, stream>>>(Wm, bm, Wf, bf, weff);
  k_rec<<<8, 512, 0, stream>>>(gx3, Whh, bhh, weff, hx, out);
}